// Round 9
// baseline (1047.373 us; speedup 1.0000x reference)
//
#include <hip/hip_runtime.h>
#include <hip/hip_bf16.h>
#include <math.h>

#define BB 8
#define LL 2048
#define LH 1024            // half sequence (recurrence runs in two passes)
#define DD 128

// ---------------------------------------------------------------------------
// DPP helpers: full-rate VALU cross-lane adds (no LDS in the serial chain).
// ---------------------------------------------------------------------------
template <int CTRL>
__device__ __forceinline__ float dpp_add(float x) {
    int xi = __float_as_int(x);
    int yi = __builtin_amdgcn_update_dpp(xi, xi, CTRL, 0xF, 0xF, false);
    return x + __int_as_float(yi);
}
// 16-lane allreduce: ^1, ^2 (quad_perm), ^:8 (half_mirror), ^:16 (mirror)
__device__ __forceinline__ float allreduce16(float p) {
    p = dpp_add<0xB1>(p);
    p = dpp_add<0x4E>(p);
    p = dpp_add<0x141>(p);
    p = dpp_add<0x140>(p);
    return p;
}
__device__ __forceinline__ float rlane(float p, int l) {
    return __int_as_float(__builtin_amdgcn_readlane(__float_as_int(p), l));
}

// ---------------------------------------------------------------------------
// C[M,O] = X @ W[O,128]^T, optional sigmoid. X rows addressed with (batch,
// half) strides so the scattered oc layout works: row m -> b=m>>11, t=m&2047,
// h=t>>10, tl=t&1023; addr = X + b*sB + h*sH + tl*ldx.
// ---------------------------------------------------------------------------
__global__ __launch_bounds__(256) void gemm_kernel(
    const float* __restrict__ X, long ldx, long sB, long sH,
    const float* __restrict__ W,
    float* __restrict__ C, int ldc,
    int applySig)
{
    __shared__ float Xs[32 * 132];
    __shared__ float Ws[64 * 132];
    const int tid = threadIdx.x;
    const int m0 = blockIdx.x * 32;
    const int o0 = blockIdx.y * 64;
    {
        int row = tid >> 3, cg = tid & 7;
        int m = m0 + row;
        int b = m >> 11, t = m & 2047, h = t >> 10, tl = t & 1023;
        const float* src = X + (size_t)b * sB + (size_t)h * sH
                             + (size_t)tl * ldx + cg * 16;
        float* dst = Xs + row * 132 + cg * 16;
#pragma unroll
        for (int u = 0; u < 4; ++u)
            *(float4*)(dst + 4 * u) = *(const float4*)(src + 4 * u);
    }
    {
        int o = tid >> 2, cg = tid & 3;
        const float* src = W + (size_t)(o0 + o) * 128 + cg * 32;
        float* dst = Ws + o * 132 + cg * 32;
#pragma unroll
        for (int u = 0; u < 8; ++u)
            *(float4*)(dst + 4 * u) = *(const float4*)(src + 4 * u);
    }
    __syncthreads();
    const int tx = tid & 31, ty = tid >> 5;
    float acc[4][2] = {};
    const float* xb = Xs + (ty * 4) * 132;
    const float* wb = Ws + (tx * 2) * 132;
    for (int k0 = 0; k0 < 128; k0 += 4) {
        float4 xr[4], wr[2];
#pragma unroll
        for (int r = 0; r < 4; ++r) xr[r] = *(const float4*)(xb + r * 132 + k0);
#pragma unroll
        for (int cc = 0; cc < 2; ++cc) wr[cc] = *(const float4*)(wb + cc * 132 + k0);
#pragma unroll
        for (int r = 0; r < 4; ++r)
#pragma unroll
            for (int cc = 0; cc < 2; ++cc) {
                acc[r][cc] += xr[r].x * wr[cc].x + xr[r].y * wr[cc].y
                            + xr[r].z * wr[cc].z + xr[r].w * wr[cc].w;
            }
    }
#pragma unroll
    for (int r = 0; r < 4; ++r)
#pragma unroll
        for (int cc = 0; cc < 2; ++cc) {
            float v = acc[r][cc];
            if (applySig) v = 1.0f / (1.0f + __expf(-v));
            C[(size_t)(m0 + ty * 4 + r) * ldc + o0 + tx * 2 + cc] = v;
        }
}

// ---------------------------------------------------------------------------
// Depthwise conv(K=3) + sigmoid + L2-norm for q,k; packs the recurrence
// stream:  pack[M,640] = [ k(128) | m=beta*k(128) | alpha(128) | q(128) | v(128) ]
// ---------------------------------------------------------------------------
__global__ __launch_bounds__(256) void convnorm_kernel(
    const float* __restrict__ qkv,
    const float* __restrict__ qw, const float* __restrict__ qb,
    const float* __restrict__ kw, const float* __restrict__ kb,
    const float* __restrict__ ab,
    float* __restrict__ pack)
{
    const int tid = threadIdx.x;
    const int lane = tid & 63;
    const int wid = tid >> 6;
    const int m = blockIdx.x * 4 + wid;     // b*L + l
    const int l = m & (LL - 1);
    const int d0 = lane * 2;
    float yq0 = qb[d0], yq1 = qb[d0 + 1];
    float yk0 = kb[d0], yk1 = kb[d0 + 1];
#pragma unroll
    for (int tau = 0; tau < 3; ++tau) {
        int lp = l + tau - 1;
        if (lp >= 0 && lp < LL) {
            const float* base = qkv + (size_t)(m + tau - 1) * 512;
            yq0 += base[d0]       * qw[d0 * 3 + tau];
            yq1 += base[d0 + 1]   * qw[(d0 + 1) * 3 + tau];
            yk0 += base[128 + d0]     * kw[d0 * 3 + tau];
            yk1 += base[128 + d0 + 1] * kw[(d0 + 1) * 3 + tau];
        }
    }
    yq0 = 1.0f / (1.0f + __expf(-yq0));
    yq1 = 1.0f / (1.0f + __expf(-yq1));
    yk0 = 1.0f / (1.0f + __expf(-yk0));
    yk1 = 1.0f / (1.0f + __expf(-yk1));
    float sq = yq0 * yq0 + yq1 * yq1;
    float sk = yk0 * yk0 + yk1 * yk1;
#pragma unroll
    for (int msk = 1; msk <= 32; msk <<= 1) {
        sq += __shfl_xor(sq, msk);
        sk += __shfl_xor(sk, msk);
    }
    float rq = 1.0f / fmaxf(sqrtf(sq), 1e-12f);
    float rk = 1.0f / fmaxf(sqrtf(sk), 1e-12f);
    float k0n = yk0 * rk, k1n = yk1 * rk;
    float a0 = ab[(size_t)m * 256 + d0];
    float a1 = ab[(size_t)m * 256 + d0 + 1];
    float b0 = ab[(size_t)m * 256 + 128 + d0];
    float b1 = ab[(size_t)m * 256 + 128 + d0 + 1];
    float v0 = qkv[(size_t)m * 512 + 256 + d0];
    float v1 = qkv[(size_t)m * 512 + 256 + d0 + 1];
    float* P = pack + (size_t)m * 640;
    P[d0]       = k0n;      P[d0 + 1]       = k1n;
    P[128 + d0] = b0 * k0n; P[128 + d0 + 1] = b1 * k1n;
    P[256 + d0] = a0;       P[256 + d0 + 1] = a1;
    P[384 + d0] = yq0 * rq; P[384 + d0 + 1] = yq1 * rq;
    P[512 + d0] = v0;       P[512 + d0 + 1] = v1;
}

// ---------------------------------------------------------------------------
// Barrier-free delta-rule recurrence, R=2 rows/wave, HALF sequence per call.
// Grid 512 = BB*64 one-wave WGs (2 WGs/CU). Lane layouts:
//   A: iA=lane>>5, c=lane&31: holds S[rbase+iA][4c..4c+4)     -> SA[4]
//      (dot; allreduce16 -> 4 group sums; 4 readlanes -> sk0, sk1)
//   B: lane holds cols {2*lane, 2*lane+1} of both rows        -> SB[2][2]
// Partials: bf16 (R8 lesson: fp8 quantization of 64 partials -> 0.176 fail).
// pout[g][b][tl][d], g in [0,64), tl in [0,LH). State: sin -> regs -> sout
// (reads complete before any writes; waves own disjoint row slices).
// ---------------------------------------------------------------------------
__global__ __launch_bounds__(64) void recur2_kernel(
    const float* __restrict__ pack, const float* __restrict__ sin,
    __hip_bfloat16* __restrict__ pout, float* __restrict__ sout, int t0)
{
    const int lane = threadIdx.x;
    const int b = blockIdx.x >> 6;
    const int g = blockIdx.x & 63;
    const int rbase = g * 2;
    const int iA = lane >> 5;
    const int c  = lane & 31;
    const int colA = c * 4;
    const int j0 = lane * 2;

    float SA[4];
    {
        const float* sp = sin + ((size_t)b * DD + rbase + iA) * DD + colA;
        float4 t4 = *(const float4*)sp;
        SA[0] = t4.x; SA[1] = t4.y; SA[2] = t4.z; SA[3] = t4.w;
    }
    float SB[2][2];
#pragma unroll
    for (int r = 0; r < 2; ++r) {
        const float* sp = sin + ((size_t)b * DD + rbase + r) * DD + j0;
        float2 t2 = *(const float2*)(sp);
        SB[r][0] = t2.x; SB[r][1] = t2.y;
    }

    const float* P = pack + ((size_t)b * LL + t0) * 640;
    __hip_bfloat16* po = pout + ((size_t)g * (BB * LH) + (size_t)b * LH) * DD + j0;

    float ka[2][4], ma[2][4], aa[2][4];
    float qv[2][2], vv[2][2], aB[2][2], mB[2][2];

#define PRE(BF)                                                              \
    do {                                                                     \
        float4 t4 = *(const float4*)(P + colA);                              \
        ka[BF][0] = t4.x; ka[BF][1] = t4.y; ka[BF][2] = t4.z; ka[BF][3] = t4.w; \
        t4 = *(const float4*)(P + 128 + colA);                               \
        ma[BF][0] = t4.x; ma[BF][1] = t4.y; ma[BF][2] = t4.z; ma[BF][3] = t4.w; \
        t4 = *(const float4*)(P + 256 + colA);                               \
        aa[BF][0] = t4.x; aa[BF][1] = t4.y; aa[BF][2] = t4.z; aa[BF][3] = t4.w; \
        float2 t2 = *(const float2*)(P + 384 + rbase);                       \
        qv[BF][0] = t2.x; qv[BF][1] = t2.y;                                  \
        t2 = *(const float2*)(P + 512 + rbase);                              \
        vv[BF][0] = t2.x; vv[BF][1] = t2.y;                                  \
        t2 = *(const float2*)(P + 256 + j0);                                 \
        aB[BF][0] = t2.x; aB[BF][1] = t2.y;                                  \
        t2 = *(const float2*)(P + 128 + j0);                                 \
        mB[BF][0] = t2.x; mB[BF][1] = t2.y;                                  \
        P += 640;                                                            \
    } while (0)

#define STP(BF)                                                              \
    do {                                                                     \
        float c0 = SA[0] * ka[BF][0];                                        \
        float c1 = SA[1] * ka[BF][1];                                        \
        c0 = fmaf(SA[2], ka[BF][2], c0);                                     \
        c1 = fmaf(SA[3], ka[BF][3], c1);                                     \
        float p = c0 + c1;                                                   \
        p = allreduce16(p);                                                  \
        float sk0 = rlane(p, 0)  + rlane(p, 16);                             \
        float sk1 = rlane(p, 32) + rlane(p, 48);                             \
        float pown = iA ? sk1 : sk0;                                         \
        float vA   = iA ? vv[BF][1] : vv[BF][0];                             \
        _Pragma("unroll")                                                    \
        for (int u = 0; u < 4; ++u) {                                        \
            float w = fmaf(-aa[BF][u], pown, vA);                            \
            SA[u] = fmaf(ma[BF][u], w, aa[BF][u] * SA[u]);                   \
        }                                                                    \
        float po0 = 0.0f, po1 = 0.0f;                                        \
        _Pragma("unroll")                                                    \
        for (int r = 0; r < 2; ++r) {                                        \
            float skr = r ? sk1 : sk0;                                       \
            float w0 = fmaf(-aB[BF][0], skr, vv[BF][r]);                     \
            SB[r][0] = fmaf(mB[BF][0], w0, aB[BF][0] * SB[r][0]);            \
            po0 = fmaf(qv[BF][r], SB[r][0], po0);                            \
            float w1 = fmaf(-aB[BF][1], skr, vv[BF][r]);                     \
            SB[r][1] = fmaf(mB[BF][1], w1, aB[BF][1] * SB[r][1]);            \
            po1 = fmaf(qv[BF][r], SB[r][1], po1);                            \
        }                                                                    \
        __hip_bfloat162 h2;                                                  \
        h2.x = __float2bfloat16(po0);                                        \
        h2.y = __float2bfloat16(po1);                                        \
        *(__hip_bfloat162*)po = h2;                                          \
        po += DD;                                                            \
    } while (0)

    PRE(0);     // t0
    PRE(1);     // t0+1
    for (int t = 0; t < LH; t += 2) {
        STP(0);
        PRE(0);     // t0+t+2 (tail overrun reads stay inside ws: unused)
        STP(1);
        PRE(1);     // t0+t+3
    }
#undef PRE
#undef STP

    {
        float* sp = sout + ((size_t)b * DD + rbase + iA) * DD + colA;
        float4 o4 = {SA[0], SA[1], SA[2], SA[3]};
        *(float4*)sp = o4;
    }
}

// ---------------------------------------------------------------------------
// oc(half) = silu(sum_{g<64} pout[g])  bf16 -> fp32. Writes into the DEAD
// half-band of pack: oc(b,h,tl,d) = ocbase[b*2048*640 + h*1024*640 + tl*128 + d].
// ---------------------------------------------------------------------------
__global__ __launch_bounds__(256) void combine_silu_kernel(
    const ushort* __restrict__ pout, float* __restrict__ ocbase, int h)
{
    const size_t NHALF = (size_t)BB * LH * DD;   // elems per slice
    size_t idx = ((size_t)blockIdx.x * 256 + threadIdx.x) * 4;
    float s0 = 0, s1 = 0, s2 = 0, s3 = 0;
#pragma unroll 8
    for (int gi = 0; gi < 64; ++gi) {
        uint2 u = *(const uint2*)(pout + gi * NHALF + idx);
        s0 += __uint_as_float((u.x & 0xffffu) << 16);
        s1 += __uint_as_float(u.x & 0xffff0000u);
        s2 += __uint_as_float((u.y & 0xffffu) << 16);
        s3 += __uint_as_float(u.y & 0xffff0000u);
    }
    float4 r;
    r.x = s0 / (1.0f + __expf(-s0));
    r.y = s1 / (1.0f + __expf(-s1));
    r.z = s2 / (1.0f + __expf(-s2));
    r.w = s3 / (1.0f + __expf(-s3));
    size_t b = idx >> 17;                // / (LH*DD)
    size_t rem = idx & ((size_t)LH * DD - 1);
    float* dst = ocbase + b * (2048ull * 640) + (size_t)h * (1024ull * 640) + rem;
    *(float4*)dst = r;
}

// ---------------------------------------------------------------------------
// d_out = y * rsqrt(mean(y^2)+1e-6) * rms_w + residual. One wave per (b,l).
// ---------------------------------------------------------------------------
__global__ __launch_bounds__(256) void rms_res_kernel(
    const float* __restrict__ y, const float* __restrict__ res,
    const float* __restrict__ rmsw, float* __restrict__ out)
{
    const int tid = threadIdx.x;
    const int lane = tid & 63;
    const int wid = tid >> 6;
    const int m = blockIdx.x * 4 + wid;
    const int d0 = lane * 2;
    size_t o = (size_t)m * DD + d0;
    float2 yv = *(const float2*)(y + o);
    float ss = yv.x * yv.x + yv.y * yv.y;
#pragma unroll
    for (int msk = 1; msk <= 32; msk <<= 1) ss += __shfl_xor(ss, msk);
    float r = rsqrtf(ss * (1.0f / 128.0f) + 1e-6f);
    float2 rv = *(const float2*)(res + o);
    out[o]     = yv.x * r * rmsw[d0]     + rv.x;
    out[o + 1] = yv.y * r * rmsw[d0 + 1] + rv.y;
}

// ---------------------------------------------------------------------------
// Workspace (176,160,768 B total — identical to the R7-proven footprint):
//   [0, 41.9MB)   pack [M,640] fp32. After each half's recurrence, that
//                 half's band per batch is dead -> combine writes oc there.
//   [41.9MB, +134.2MB) poreg:
//      phase 1:  qkv [M,512] + abv [M,256]
//      phase 2:  pout bf16, 64 slices x [B,LH,D]   (reused for both halves)
//      phase 3:  res [M,128] + yb [M,128]
// Mid-sequence state lives in sfin (inside d_out): written h0, read h1.
// ---------------------------------------------------------------------------
extern "C" void kernel_launch(void* const* d_in, const int* in_sizes, int n_in,
                              void* d_out, int out_size, void* d_ws, size_t ws_size,
                              hipStream_t stream)
{
    const float* x      = (const float*)d_in[0];
    const float* state  = (const float*)d_in[1];
    const float* W_in   = (const float*)d_in[2];
    const float* W_gate = (const float*)d_in[3];
    const float* W_out  = (const float*)d_in[4];
    const float* W_res  = (const float*)d_in[5];
    const float* qcw    = (const float*)d_in[6];
    const float* qcb    = (const float*)d_in[7];
    const float* kcw    = (const float*)d_in[8];
    const float* kcb    = (const float*)d_in[9];
    const float* rmsw   = (const float*)d_in[10];
    float* out  = (float*)d_out;
    float* sfin = out + (size_t)BB * LL * DD;

    const size_t M = (size_t)BB * LL;            // 16384
    char* base = (char*)d_ws;
    const size_t PACK_BYTES = M * 640 * 4;       // 41.9 MB
    float* pack = (float*)base;
    char*  poreg = base + PACK_BYTES;
    float* qkv = (float*)poreg;                              // phase 1
    float* abv = (float*)(poreg + M * 512 * 4);              // phase 1
    __hip_bfloat16* po = (__hip_bfloat16*)poreg;             // phase 2
    float* res = (float*)poreg;                              // phase 3 (over po)
    float* yb  = (float*)(poreg + M * DD * 4);               // phase 3

    const long ld128 = 128, ld512 = 512;
    dim3 blk(256);
    // qkv = x @ W_in^T  [M,512]
    gemm_kernel<<<dim3(M / 32, 8), blk, 0, stream>>>(
        x, ld128, 2048 * ld128, 1024 * ld128, W_in, qkv, 512, 0);
    // alpha/beta = sigmoid(gate @ W_gate^T) [M,256]
    gemm_kernel<<<dim3(M / 32, 4), blk, 0, stream>>>(
        qkv + 384, ld512, 2048 * ld512, 1024 * ld512, W_gate, abv, 256, 1);
    // conv + sigmoid + l2norm + pack stream [k|m|alpha|q|v]
    convnorm_kernel<<<dim3(M / 4), blk, 0, stream>>>(qkv, qcw, qcb, kcw, kcb, abv, pack);
    // recurrence half 0: state -> sfin(mid), partials -> po
    recur2_kernel<<<dim3(BB * 64), dim3(64), 0, stream>>>(pack, state, po, sfin, 0);
    // combine h0 -> oc half 0 (into pack's dead t<1024 bands)
    combine_silu_kernel<<<dim3((BB * LH * DD) / 1024), blk, 0, stream>>>(
        (const ushort*)po, pack, 0);
    // recurrence half 1: sfin(mid) -> sfin(final), partials -> po (reused)
    recur2_kernel<<<dim3(BB * 64), dim3(64), 0, stream>>>(pack, sfin, po, sfin, LH);
    // combine h1 -> oc half 1
    combine_silu_kernel<<<dim3((BB * LH * DD) / 1024), blk, 0, stream>>>(
        (const ushort*)po, pack, 1);
    // residual = x @ W_res^T  (po region dead after combine h1)
    gemm_kernel<<<dim3(M / 32, 2), blk, 0, stream>>>(
        x, ld128, 2048 * ld128, 1024 * ld128, W_res, res, 128, 0);
    // y = oc @ W_out^T   (oc scattered in pack: sB=2048*640, sH=1024*640)
    gemm_kernel<<<dim3(M / 32, 2), blk, 0, stream>>>(
        pack, ld128, 2048 * 640, 1024 * 640, W_out, yb, 128, 0);
    // RMS + residual -> d_out
    rms_res_kernel<<<dim3(M / 4), blk, 0, stream>>>(yb, res, rmsw, out);
}

// Round 10
// 665.673 us; speedup vs baseline: 1.5734x; 1.5734x over previous
//
#include <hip/hip_runtime.h>
#include <hip/hip_bf16.h>
#include <math.h>

#define BB 8
#define LL 2048
#define LH 1024            // half sequence (recurrence runs in two passes)
#define DD 128

// ---------------------------------------------------------------------------
// DPP helpers: full-rate VALU cross-lane adds (no LDS in the serial chain).
// ---------------------------------------------------------------------------
template <int CTRL>
__device__ __forceinline__ float dpp_add(float x) {
    int xi = __float_as_int(x);
    int yi = __builtin_amdgcn_update_dpp(xi, xi, CTRL, 0xF, 0xF, false);
    return x + __int_as_float(yi);
}
// 16-lane allreduce: ^1, ^2 (quad_perm), ^:8 (half_mirror), ^:16 (mirror)
__device__ __forceinline__ float allreduce16(float p) {
    p = dpp_add<0xB1>(p);
    p = dpp_add<0x4E>(p);
    p = dpp_add<0x141>(p);
    p = dpp_add<0x140>(p);
    return p;
}
__device__ __forceinline__ float rlane(float p, int l) {
    return __int_as_float(__builtin_amdgcn_readlane(__float_as_int(p), l));
}

// ---------------------------------------------------------------------------
// C[M,O] = X @ W[O,128]^T, optional sigmoid. X rows addressed with (batch,
// half) strides so the scattered oc layout works: row m -> b=m>>11, t=m&2047,
// h=t>>10, tl=t&1023; addr = X + b*sB + h*sH + tl*ldx.
// ---------------------------------------------------------------------------
__global__ __launch_bounds__(256) void gemm_kernel(
    const float* __restrict__ X, long ldx, long sB, long sH,
    const float* __restrict__ W,
    float* __restrict__ C, int ldc,
    int applySig)
{
    __shared__ float Xs[32 * 132];
    __shared__ float Ws[64 * 132];
    const int tid = threadIdx.x;
    const int m0 = blockIdx.x * 32;
    const int o0 = blockIdx.y * 64;
    {
        int row = tid >> 3, cg = tid & 7;
        int m = m0 + row;
        int b = m >> 11, t = m & 2047, h = t >> 10, tl = t & 1023;
        const float* src = X + (size_t)b * sB + (size_t)h * sH
                             + (size_t)tl * ldx + cg * 16;
        float* dst = Xs + row * 132 + cg * 16;
#pragma unroll
        for (int u = 0; u < 4; ++u)
            *(float4*)(dst + 4 * u) = *(const float4*)(src + 4 * u);
    }
    {
        int o = tid >> 2, cg = tid & 3;
        const float* src = W + (size_t)(o0 + o) * 128 + cg * 32;
        float* dst = Ws + o * 132 + cg * 32;
#pragma unroll
        for (int u = 0; u < 8; ++u)
            *(float4*)(dst + 4 * u) = *(const float4*)(src + 4 * u);
    }
    __syncthreads();
    const int tx = tid & 31, ty = tid >> 5;
    float acc[4][2] = {};
    const float* xb = Xs + (ty * 4) * 132;
    const float* wb = Ws + (tx * 2) * 132;
    for (int k0 = 0; k0 < 128; k0 += 4) {
        float4 xr[4], wr[2];
#pragma unroll
        for (int r = 0; r < 4; ++r) xr[r] = *(const float4*)(xb + r * 132 + k0);
#pragma unroll
        for (int cc = 0; cc < 2; ++cc) wr[cc] = *(const float4*)(wb + cc * 132 + k0);
#pragma unroll
        for (int r = 0; r < 4; ++r)
#pragma unroll
            for (int cc = 0; cc < 2; ++cc) {
                acc[r][cc] += xr[r].x * wr[cc].x + xr[r].y * wr[cc].y
                            + xr[r].z * wr[cc].z + xr[r].w * wr[cc].w;
            }
    }
#pragma unroll
    for (int r = 0; r < 4; ++r)
#pragma unroll
        for (int cc = 0; cc < 2; ++cc) {
            float v = acc[r][cc];
            if (applySig) v = 1.0f / (1.0f + __expf(-v));
            C[(size_t)(m0 + ty * 4 + r) * ldc + o0 + tx * 2 + cc] = v;
        }
}

// ---------------------------------------------------------------------------
// Depthwise conv(K=3) + sigmoid + L2-norm for q,k; packs the recurrence
// stream TIME-BLOCKED (TB=4): for batch b, block tb=t>>2, ti=t&3:
//   pack2[(b*512 + tb)*2560 + (o*128 + d)*4 + ti],  o in {k,m,a,q,v}
// so one float4 load in the recurrence yields 4 timesteps of one scalar.
// ---------------------------------------------------------------------------
__global__ __launch_bounds__(256) void convnorm_kernel(
    const float* __restrict__ qkv,
    const float* __restrict__ qw, const float* __restrict__ qb,
    const float* __restrict__ kw, const float* __restrict__ kb,
    const float* __restrict__ ab,
    float* __restrict__ pack)
{
    const int tid = threadIdx.x;
    const int lane = tid & 63;
    const int wid = tid >> 6;
    const int m = blockIdx.x * 4 + wid;     // b*L + l
    const int l = m & (LL - 1);
    const int b = m >> 11;
    const int d0 = lane * 2;
    float yq0 = qb[d0], yq1 = qb[d0 + 1];
    float yk0 = kb[d0], yk1 = kb[d0 + 1];
#pragma unroll
    for (int tau = 0; tau < 3; ++tau) {
        int lp = l + tau - 1;
        if (lp >= 0 && lp < LL) {
            const float* base = qkv + (size_t)(m + tau - 1) * 512;
            yq0 += base[d0]       * qw[d0 * 3 + tau];
            yq1 += base[d0 + 1]   * qw[(d0 + 1) * 3 + tau];
            yk0 += base[128 + d0]     * kw[d0 * 3 + tau];
            yk1 += base[128 + d0 + 1] * kw[(d0 + 1) * 3 + tau];
        }
    }
    yq0 = 1.0f / (1.0f + __expf(-yq0));
    yq1 = 1.0f / (1.0f + __expf(-yq1));
    yk0 = 1.0f / (1.0f + __expf(-yk0));
    yk1 = 1.0f / (1.0f + __expf(-yk1));
    float sq = yq0 * yq0 + yq1 * yq1;
    float sk = yk0 * yk0 + yk1 * yk1;
#pragma unroll
    for (int msk = 1; msk <= 32; msk <<= 1) {
        sq += __shfl_xor(sq, msk);
        sk += __shfl_xor(sk, msk);
    }
    float rq = 1.0f / fmaxf(sqrtf(sq), 1e-12f);
    float rk = 1.0f / fmaxf(sqrtf(sk), 1e-12f);
    float k0n = yk0 * rk, k1n = yk1 * rk;
    float a0 = ab[(size_t)m * 256 + d0];
    float a1 = ab[(size_t)m * 256 + d0 + 1];
    float b0 = ab[(size_t)m * 256 + 128 + d0];
    float b1 = ab[(size_t)m * 256 + 128 + d0 + 1];
    float v0 = qkv[(size_t)m * 512 + 256 + d0];
    float v1 = qkv[(size_t)m * 512 + 256 + d0 + 1];
    float* P = pack + ((size_t)b * 512 + (l >> 2)) * 2560 + (l & 3);
    P[d0 * 4]              = k0n;      P[(d0 + 1) * 4]        = k1n;
    P[512 + d0 * 4]        = b0 * k0n; P[512 + (d0 + 1) * 4]  = b1 * k1n;
    P[1024 + d0 * 4]       = a0;       P[1024 + (d0 + 1) * 4] = a1;
    P[1536 + d0 * 4]       = yq0 * rq; P[1536 + (d0 + 1) * 4] = yq1 * rq;
    P[2048 + d0 * 4]       = v0;       P[2048 + (d0 + 1) * 4] = v1;
}

// ---------------------------------------------------------------------------
// Barrier-free delta-rule recurrence, R=2 rows/wave, HALF sequence per call,
// TIME-BLOCKED TB=4: one PREB = 20 independent dwordx4 loads covering 4
// steps' operands; then 4 steps of pure register compute. Block-level double
// buffer (statically indexed) + __launch_bounds__(64,1) so the register
// budget lets the pipeline survive (R9: VGPR=36 proved the per-step pipeline
// collapsed; per-step time was a fixed ~900cyc latency floor at any R).
// Lane layouts (as R9, verified):
//   A: iA=lane>>5, c=lane&31: holds S[rbase+iA][4c..4c+4)     -> SA[4]
//   B: lane holds cols {2*lane, 2*lane+1} of both rows        -> SB[2][2]
// Partials: bf16. pout[g][b][tl][d]. State: sin -> regs -> sout.
// ---------------------------------------------------------------------------
__global__ __launch_bounds__(64, 1) void recur2_kernel(
    const float* __restrict__ pack, const float* __restrict__ sin,
    __hip_bfloat16* __restrict__ pout, float* __restrict__ sout, int blk0)
{
    const int lane = threadIdx.x;
    const int b = blockIdx.x >> 6;
    const int g = blockIdx.x & 63;
    const int rbase = g * 2;
    const int iA = lane >> 5;
    const int c  = lane & 31;
    const int colA = c * 4;
    const int j0 = lane * 2;

    float SA[4];
    {
        const float* sp = sin + ((size_t)b * DD + rbase + iA) * DD + colA;
        float4 t4 = *(const float4*)sp;
        SA[0] = t4.x; SA[1] = t4.y; SA[2] = t4.z; SA[3] = t4.w;
    }
    float SB[2][2];
#pragma unroll
    for (int r = 0; r < 2; ++r) {
        const float* sp = sin + ((size_t)b * DD + rbase + r) * DD + j0;
        float2 t2 = *(const float2*)(sp);
        SB[r][0] = t2.x; SB[r][1] = t2.y;
    }

    const float* P = pack + ((size_t)b * 512 + blk0) * 2560;
    __hip_bfloat16* po = pout + ((size_t)g * (BB * LH) + (size_t)b * LH) * DD + j0;

    // block-level double buffers (statically indexed; ~160 VGPR at (64,1))
    float4 ka4[2][4], ma4[2][4], aa4[2][4];
    float4 qv4[2][2], vv4[2][2], aB4[2][2], mB4[2][2];

#define PREB(BF)                                                             \
    do {                                                                     \
        _Pragma("unroll")                                                    \
        for (int u = 0; u < 4; ++u) {                                        \
            ka4[BF][u] = *(const float4*)(P + (colA + u) * 4);               \
            ma4[BF][u] = *(const float4*)(P + 512 + (colA + u) * 4);         \
            aa4[BF][u] = *(const float4*)(P + 1024 + (colA + u) * 4);        \
        }                                                                    \
        qv4[BF][0] = *(const float4*)(P + 1536 + rbase * 4);                 \
        qv4[BF][1] = *(const float4*)(P + 1536 + rbase * 4 + 4);             \
        vv4[BF][0] = *(const float4*)(P + 2048 + rbase * 4);                 \
        vv4[BF][1] = *(const float4*)(P + 2048 + rbase * 4 + 4);             \
        aB4[BF][0] = *(const float4*)(P + 1024 + j0 * 4);                    \
        aB4[BF][1] = *(const float4*)(P + 1024 + j0 * 4 + 4);                \
        mB4[BF][0] = *(const float4*)(P + 512 + j0 * 4);                     \
        mB4[BF][1] = *(const float4*)(P + 512 + j0 * 4 + 4);                 \
        P += 2560;                                                           \
    } while (0)

#define STEPQ(BF, CMP)                                                       \
    do {                                                                     \
        float e0 = SA[0] * ka4[BF][0].CMP;                                   \
        float e1 = SA[1] * ka4[BF][1].CMP;                                   \
        e0 = fmaf(SA[2], ka4[BF][2].CMP, e0);                                \
        e1 = fmaf(SA[3], ka4[BF][3].CMP, e1);                                \
        float p = e0 + e1;                                                   \
        p = allreduce16(p);                                                  \
        float sk0 = rlane(p, 0)  + rlane(p, 16);                             \
        float sk1 = rlane(p, 32) + rlane(p, 48);                             \
        float pown = iA ? sk1 : sk0;                                         \
        float vA   = iA ? vv4[BF][1].CMP : vv4[BF][0].CMP;                   \
        _Pragma("unroll")                                                    \
        for (int u = 0; u < 4; ++u) {                                        \
            float au = aa4[BF][u].CMP;                                       \
            float w = fmaf(-au, pown, vA);                                   \
            SA[u] = fmaf(ma4[BF][u].CMP, w, au * SA[u]);                     \
        }                                                                    \
        float aB0 = aB4[BF][0].CMP, aB1 = aB4[BF][1].CMP;                    \
        float mB0 = mB4[BF][0].CMP, mB1 = mB4[BF][1].CMP;                    \
        float po0 = 0.0f, po1 = 0.0f;                                        \
        _Pragma("unroll")                                                    \
        for (int r = 0; r < 2; ++r) {                                        \
            float skr = r ? sk1 : sk0;                                       \
            float vvr = r ? vv4[BF][1].CMP : vv4[BF][0].CMP;                 \
            float qvr = r ? qv4[BF][1].CMP : qv4[BF][0].CMP;                 \
            float w0 = fmaf(-aB0, skr, vvr);                                 \
            SB[r][0] = fmaf(mB0, w0, aB0 * SB[r][0]);                        \
            po0 = fmaf(qvr, SB[r][0], po0);                                  \
            float w1 = fmaf(-aB1, skr, vvr);                                 \
            SB[r][1] = fmaf(mB1, w1, aB1 * SB[r][1]);                        \
            po1 = fmaf(qvr, SB[r][1], po1);                                  \
        }                                                                    \
        __hip_bfloat162 h2;                                                  \
        h2.x = __float2bfloat16(po0);                                        \
        h2.y = __float2bfloat16(po1);                                        \
        *(__hip_bfloat162*)po = h2;                                          \
        po += DD;                                                            \
    } while (0)

#define STEP4(BF) \
    do { STEPQ(BF, x); STEPQ(BF, y); STEPQ(BF, z); STEPQ(BF, w); } while (0)

    PREB(0);    // block blk0
    PREB(1);    // block blk0+1
    for (int tb = 0; tb < LH / 4; tb += 2) {
        STEP4(0);
        PREB(0);    // blk+2 (final iters overrun into ws: values unused)
        STEP4(1);
        PREB(1);    // blk+3
    }
#undef PREB
#undef STEPQ
#undef STEP4

    {
        float* sp = sout + ((size_t)b * DD + rbase + iA) * DD + colA;
        float4 o4 = {SA[0], SA[1], SA[2], SA[3]};
        *(float4*)sp = o4;
    }
}

// ---------------------------------------------------------------------------
// oc(half) = silu(sum_{g<64} pout[g])  bf16 -> fp32. Writes into the DEAD
// half-band of pack: oc(b,h,tl,d) = ocbase[b*2048*640 + h*1024*640 + tl*128 + d]
// (same byte range as the blocked pack layout's (b, tb<256|>=256) bands).
// ---------------------------------------------------------------------------
__global__ __launch_bounds__(256) void combine_silu_kernel(
    const ushort* __restrict__ pout, float* __restrict__ ocbase, int h)
{
    const size_t NHALF = (size_t)BB * LH * DD;   // elems per slice
    size_t idx = ((size_t)blockIdx.x * 256 + threadIdx.x) * 4;
    float s0 = 0, s1 = 0, s2 = 0, s3 = 0;
#pragma unroll 8
    for (int gi = 0; gi < 64; ++gi) {
        uint2 u = *(const uint2*)(pout + gi * NHALF + idx);
        s0 += __uint_as_float((u.x & 0xffffu) << 16);
        s1 += __uint_as_float(u.x & 0xffff0000u);
        s2 += __uint_as_float((u.y & 0xffffu) << 16);
        s3 += __uint_as_float(u.y & 0xffff0000u);
    }
    float4 r;
    r.x = s0 / (1.0f + __expf(-s0));
    r.y = s1 / (1.0f + __expf(-s1));
    r.z = s2 / (1.0f + __expf(-s2));
    r.w = s3 / (1.0f + __expf(-s3));
    size_t b = idx >> 17;                // / (LH*DD)
    size_t rem = idx & ((size_t)LH * DD - 1);
    float* dst = ocbase + b * (2048ull * 640) + (size_t)h * (1024ull * 640) + rem;
    *(float4*)dst = r;
}

// ---------------------------------------------------------------------------
// d_out = y * rsqrt(mean(y^2)+1e-6) * rms_w + residual. One wave per (b,l).
// ---------------------------------------------------------------------------
__global__ __launch_bounds__(256) void rms_res_kernel(
    const float* __restrict__ y, const float* __restrict__ res,
    const float* __restrict__ rmsw, float* __restrict__ out)
{
    const int tid = threadIdx.x;
    const int lane = tid & 63;
    const int wid = tid >> 6;
    const int m = blockIdx.x * 4 + wid;
    const int d0 = lane * 2;
    size_t o = (size_t)m * DD + d0;
    float2 yv = *(const float2*)(y + o);
    float ss = yv.x * yv.x + yv.y * yv.y;
#pragma unroll
    for (int msk = 1; msk <= 32; msk <<= 1) ss += __shfl_xor(ss, msk);
    float r = rsqrtf(ss * (1.0f / 128.0f) + 1e-6f);
    float2 rv = *(const float2*)(res + o);
    out[o]     = yv.x * r * rmsw[d0]     + rv.x;
    out[o + 1] = yv.y * r * rmsw[d0 + 1] + rv.y;
}

// ---------------------------------------------------------------------------
// Workspace (176,160,768 B total — the R7/R9-proven footprint):
//   [0, 41.9MB)   pack2 blocked [B,512,2560] fp32. After each half's
//                 recurrence that half's band is dead -> combine writes oc.
//   [41.9MB, +134.2MB) poreg:
//      phase 1:  qkv [M,512] + abv [M,256]
//      phase 2:  pout bf16, 64 slices x [B,LH,D]   (reused both halves)
//      phase 3:  res [M,128] + yb [M,128]
// Mid-sequence state lives in sfin (inside d_out): written h0, read h1.
// ---------------------------------------------------------------------------
extern "C" void kernel_launch(void* const* d_in, const int* in_sizes, int n_in,
                              void* d_out, int out_size, void* d_ws, size_t ws_size,
                              hipStream_t stream)
{
    const float* x      = (const float*)d_in[0];
    const float* state  = (const float*)d_in[1];
    const float* W_in   = (const float*)d_in[2];
    const float* W_gate = (const float*)d_in[3];
    const float* W_out  = (const float*)d_in[4];
    const float* W_res  = (const float*)d_in[5];
    const float* qcw    = (const float*)d_in[6];
    const float* qcb    = (const float*)d_in[7];
    const float* kcw    = (const float*)d_in[8];
    const float* kcb    = (const float*)d_in[9];
    const float* rmsw   = (const float*)d_in[10];
    float* out  = (float*)d_out;
    float* sfin = out + (size_t)BB * LL * DD;

    const size_t M = (size_t)BB * LL;            // 16384
    char* base = (char*)d_ws;
    const size_t PACK_BYTES = M * 640 * 4;       // 41.9 MB
    float* pack = (float*)base;
    char*  poreg = base + PACK_BYTES;
    float* qkv = (float*)poreg;                              // phase 1
    float* abv = (float*)(poreg + M * 512 * 4);              // phase 1
    __hip_bfloat16* po = (__hip_bfloat16*)poreg;             // phase 2
    float* res = (float*)poreg;                              // phase 3 (over po)
    float* yb  = (float*)(poreg + M * DD * 4);               // phase 3

    const long ld128 = 128, ld512 = 512;
    dim3 blk(256);
    // qkv = x @ W_in^T  [M,512]
    gemm_kernel<<<dim3(M / 32, 8), blk, 0, stream>>>(
        x, ld128, 2048 * ld128, 1024 * ld128, W_in, qkv, 512, 0);
    // alpha/beta = sigmoid(gate @ W_gate^T) [M,256]
    gemm_kernel<<<dim3(M / 32, 4), blk, 0, stream>>>(
        qkv + 384, ld512, 2048 * ld512, 1024 * ld512, W_gate, abv, 256, 1);
    // conv + sigmoid + l2norm + blocked pack stream [k|m|alpha|q|v] x TB=4
    convnorm_kernel<<<dim3(M / 4), blk, 0, stream>>>(qkv, qcw, qcb, kcw, kcb, abv, pack);
    // recurrence half 0: state -> sfin(mid), partials -> po
    recur2_kernel<<<dim3(BB * 64), dim3(64), 0, stream>>>(pack, state, po, sfin, 0);
    // combine h0 -> oc half 0 (into pack's dead tb<256 bands)
    combine_silu_kernel<<<dim3((BB * LH * DD) / 1024), blk, 0, stream>>>(
        (const ushort*)po, pack, 0);
    // recurrence half 1: sfin(mid) -> sfin(final), partials -> po (reused)
    recur2_kernel<<<dim3(BB * 64), dim3(64), 0, stream>>>(pack, sfin, po, sfin, 256);
    // combine h1 -> oc half 1
    combine_silu_kernel<<<dim3((BB * LH * DD) / 1024), blk, 0, stream>>>(
        (const ushort*)po, pack, 1);
    // residual = x @ W_res^T  (po region dead after combine h1)
    gemm_kernel<<<dim3(M / 32, 2), blk, 0, stream>>>(
        x, ld128, 2048 * ld128, 1024 * ld128, W_res, res, 128, 0);
    // y = oc @ W_out^T   (oc scattered in pack: sB=2048*640, sH=1024*640)
    gemm_kernel<<<dim3(M / 32, 2), blk, 0, stream>>>(
        pack, ld128, 2048 * 640, 1024 * 640, W_out, yb, 128, 0);
    // RMS + residual -> d_out
    rms_res_kernel<<<dim3(M / 4), blk, 0, stream>>>(yb, res, rmsw, out);
}

// Round 11
// 614.517 us; speedup vs baseline: 1.7044x; 1.0832x over previous
//
#include <hip/hip_runtime.h>
#include <hip/hip_bf16.h>
#include <math.h>

#define BB 8
#define LL 2048
#define LH 1024            // half sequence (recurrence runs in two passes)
#define DD 128

// ---------------------------------------------------------------------------
// DPP helpers: full-rate VALU cross-lane adds (no LDS in the serial chain).
// ---------------------------------------------------------------------------
template <int CTRL>
__device__ __forceinline__ float dpp_add(float x) {
    int xi = __float_as_int(x);
    int yi = __builtin_amdgcn_update_dpp(xi, xi, CTRL, 0xF, 0xF, false);
    return x + __int_as_float(yi);
}
// 16-lane allreduce: ^1, ^2 (quad_perm), ^:8 (half_mirror), ^:16 (mirror)
__device__ __forceinline__ float allreduce16(float p) {
    p = dpp_add<0xB1>(p);
    p = dpp_add<0x4E>(p);
    p = dpp_add<0x141>(p);
    p = dpp_add<0x140>(p);
    return p;
}
__device__ __forceinline__ float rlane(float p, int l) {
    return __int_as_float(__builtin_amdgcn_readlane(__float_as_int(p), l));
}

// ---------------------------------------------------------------------------
// C[M,O] = X @ W[O,128]^T, optional sigmoid. X rows addressed with (batch,
// half) strides so the scattered oc layout works: row m -> b=m>>11, t=m&2047,
// h=t>>10, tl=t&1023; addr = X + b*sB + h*sH + tl*ldx.
// ---------------------------------------------------------------------------
__global__ __launch_bounds__(256) void gemm_kernel(
    const float* __restrict__ X, long ldx, long sB, long sH,
    const float* __restrict__ W,
    float* __restrict__ C, int ldc,
    int applySig)
{
    __shared__ float Xs[32 * 132];
    __shared__ float Ws[64 * 132];
    const int tid = threadIdx.x;
    const int m0 = blockIdx.x * 32;
    const int o0 = blockIdx.y * 64;
    {
        int row = tid >> 3, cg = tid & 7;
        int m = m0 + row;
        int b = m >> 11, t = m & 2047, h = t >> 10, tl = t & 1023;
        const float* src = X + (size_t)b * sB + (size_t)h * sH
                             + (size_t)tl * ldx + cg * 16;
        float* dst = Xs + row * 132 + cg * 16;
#pragma unroll
        for (int u = 0; u < 4; ++u)
            *(float4*)(dst + 4 * u) = *(const float4*)(src + 4 * u);
    }
    {
        int o = tid >> 2, cg = tid & 3;
        const float* src = W + (size_t)(o0 + o) * 128 + cg * 32;
        float* dst = Ws + o * 132 + cg * 32;
#pragma unroll
        for (int u = 0; u < 8; ++u)
            *(float4*)(dst + 4 * u) = *(const float4*)(src + 4 * u);
    }
    __syncthreads();
    const int tx = tid & 31, ty = tid >> 5;
    float acc[4][2] = {};
    const float* xb = Xs + (ty * 4) * 132;
    const float* wb = Ws + (tx * 2) * 132;
    for (int k0 = 0; k0 < 128; k0 += 4) {
        float4 xr[4], wr[2];
#pragma unroll
        for (int r = 0; r < 4; ++r) xr[r] = *(const float4*)(xb + r * 132 + k0);
#pragma unroll
        for (int cc = 0; cc < 2; ++cc) wr[cc] = *(const float4*)(wb + cc * 132 + k0);
#pragma unroll
        for (int r = 0; r < 4; ++r)
#pragma unroll
            for (int cc = 0; cc < 2; ++cc) {
                acc[r][cc] += xr[r].x * wr[cc].x + xr[r].y * wr[cc].y
                            + xr[r].z * wr[cc].z + xr[r].w * wr[cc].w;
            }
    }
#pragma unroll
    for (int r = 0; r < 4; ++r)
#pragma unroll
        for (int cc = 0; cc < 2; ++cc) {
            float v = acc[r][cc];
            if (applySig) v = 1.0f / (1.0f + __expf(-v));
            C[(size_t)(m0 + ty * 4 + r) * ldc + o0 + tx * 2 + cc] = v;
        }
}

// ---------------------------------------------------------------------------
// Depthwise conv(K=3) + sigmoid + L2-norm for q,k; packs the recurrence
// stream TIME-BLOCKED (TB=4): for batch b, block tb=t>>2, ti=t&3:
//   pack2[(b*512 + tb)*2560 + (o*128 + d)*4 + ti],  o in {k,m,a,q,v}
// so one float4 load in the recurrence yields 4 timesteps of one scalar.
// ---------------------------------------------------------------------------
__global__ __launch_bounds__(256) void convnorm_kernel(
    const float* __restrict__ qkv,
    const float* __restrict__ qw, const float* __restrict__ qb,
    const float* __restrict__ kw, const float* __restrict__ kb,
    const float* __restrict__ ab,
    float* __restrict__ pack)
{
    const int tid = threadIdx.x;
    const int lane = tid & 63;
    const int wid = tid >> 6;
    const int m = blockIdx.x * 4 + wid;     // b*L + l
    const int l = m & (LL - 1);
    const int b = m >> 11;
    const int d0 = lane * 2;
    float yq0 = qb[d0], yq1 = qb[d0 + 1];
    float yk0 = kb[d0], yk1 = kb[d0 + 1];
#pragma unroll
    for (int tau = 0; tau < 3; ++tau) {
        int lp = l + tau - 1;
        if (lp >= 0 && lp < LL) {
            const float* base = qkv + (size_t)(m + tau - 1) * 512;
            yq0 += base[d0]       * qw[d0 * 3 + tau];
            yq1 += base[d0 + 1]   * qw[(d0 + 1) * 3 + tau];
            yk0 += base[128 + d0]     * kw[d0 * 3 + tau];
            yk1 += base[128 + d0 + 1] * kw[(d0 + 1) * 3 + tau];
        }
    }
    yq0 = 1.0f / (1.0f + __expf(-yq0));
    yq1 = 1.0f / (1.0f + __expf(-yq1));
    yk0 = 1.0f / (1.0f + __expf(-yk0));
    yk1 = 1.0f / (1.0f + __expf(-yk1));
    float sq = yq0 * yq0 + yq1 * yq1;
    float sk = yk0 * yk0 + yk1 * yk1;
#pragma unroll
    for (int msk = 1; msk <= 32; msk <<= 1) {
        sq += __shfl_xor(sq, msk);
        sk += __shfl_xor(sk, msk);
    }
    float rq = 1.0f / fmaxf(sqrtf(sq), 1e-12f);
    float rk = 1.0f / fmaxf(sqrtf(sk), 1e-12f);
    float k0n = yk0 * rk, k1n = yk1 * rk;
    float a0 = ab[(size_t)m * 256 + d0];
    float a1 = ab[(size_t)m * 256 + d0 + 1];
    float b0 = ab[(size_t)m * 256 + 128 + d0];
    float b1 = ab[(size_t)m * 256 + 128 + d0 + 1];
    float v0 = qkv[(size_t)m * 512 + 256 + d0];
    float v1 = qkv[(size_t)m * 512 + 256 + d0 + 1];
    float* P = pack + ((size_t)b * 512 + (l >> 2)) * 2560 + (l & 3);
    P[d0 * 4]              = k0n;      P[(d0 + 1) * 4]        = k1n;
    P[512 + d0 * 4]        = b0 * k0n; P[512 + (d0 + 1) * 4]  = b1 * k1n;
    P[1024 + d0 * 4]       = a0;       P[1024 + (d0 + 1) * 4] = a1;
    P[1536 + d0 * 4]       = yq0 * rq; P[1536 + (d0 + 1) * 4] = yq1 * rq;
    P[2048 + d0 * 4]       = v0;       P[2048 + (d0 + 1) * 4] = v1;
}

// ---------------------------------------------------------------------------
// Barrier-free delta-rule recurrence, R=2 rows/wave, HALF sequence per call,
// TIME-BLOCKED TB=4, depth-2 block pipeline. R10 lesson: VGPR=80 proved the
// scheduler SANK the prefetch loads into the consuming block (one exposed
// memory latency per 4 steps). Fix: __builtin_amdgcn_sched_barrier(0)
// immediately after each PREB pins the load-issue point (and forces the RA
// to keep both buffers live) without pinning the rest of the loop order.
// Lane layouts (verified R9/R10):
//   A: iA=lane>>5, c=lane&31: holds S[rbase+iA][4c..4c+4)     -> SA[4]
//   B: lane holds cols {2*lane, 2*lane+1} of both rows        -> SB[2][2]
// Partials: bf16. pout[g][b][tl][d]. State: sin -> regs -> sout.
// ---------------------------------------------------------------------------
__global__ __launch_bounds__(64, 1) void recur2_kernel(
    const float* __restrict__ pack, const float* __restrict__ sin,
    __hip_bfloat16* __restrict__ pout, float* __restrict__ sout, int blk0)
{
    const int lane = threadIdx.x;
    const int b = blockIdx.x >> 6;
    const int g = blockIdx.x & 63;
    const int rbase = g * 2;
    const int iA = lane >> 5;
    const int c  = lane & 31;
    const int colA = c * 4;
    const int j0 = lane * 2;

    float SA[4];
    {
        const float* sp = sin + ((size_t)b * DD + rbase + iA) * DD + colA;
        float4 t4 = *(const float4*)sp;
        SA[0] = t4.x; SA[1] = t4.y; SA[2] = t4.z; SA[3] = t4.w;
    }
    float SB[2][2];
#pragma unroll
    for (int r = 0; r < 2; ++r) {
        const float* sp = sin + ((size_t)b * DD + rbase + r) * DD + j0;
        float2 t2 = *(const float2*)(sp);
        SB[r][0] = t2.x; SB[r][1] = t2.y;
    }

    const float* P = pack + ((size_t)b * 512 + blk0) * 2560;
    __hip_bfloat16* po = pout + ((size_t)g * (BB * LH) + (size_t)b * LH) * DD + j0;

    // block-level double buffers (statically indexed)
    float4 ka4[2][4], ma4[2][4], aa4[2][4];
    float4 qv4[2][2], vv4[2][2], aB4[2][2], mB4[2][2];

#define PREB(BF)                                                             \
    do {                                                                     \
        _Pragma("unroll")                                                    \
        for (int u = 0; u < 4; ++u) {                                        \
            ka4[BF][u] = *(const float4*)(P + (colA + u) * 4);               \
            ma4[BF][u] = *(const float4*)(P + 512 + (colA + u) * 4);         \
            aa4[BF][u] = *(const float4*)(P + 1024 + (colA + u) * 4);        \
        }                                                                    \
        qv4[BF][0] = *(const float4*)(P + 1536 + rbase * 4);                 \
        qv4[BF][1] = *(const float4*)(P + 1536 + rbase * 4 + 4);             \
        vv4[BF][0] = *(const float4*)(P + 2048 + rbase * 4);                 \
        vv4[BF][1] = *(const float4*)(P + 2048 + rbase * 4 + 4);             \
        aB4[BF][0] = *(const float4*)(P + 1024 + j0 * 4);                    \
        aB4[BF][1] = *(const float4*)(P + 1024 + j0 * 4 + 4);                \
        mB4[BF][0] = *(const float4*)(P + 512 + j0 * 4);                     \
        mB4[BF][1] = *(const float4*)(P + 512 + j0 * 4 + 4);                 \
        P += 2560;                                                           \
        __builtin_amdgcn_sched_barrier(0);  /* pin load-issue point */       \
    } while (0)

#define STEPQ(BF, CMP)                                                       \
    do {                                                                     \
        float e0 = SA[0] * ka4[BF][0].CMP;                                   \
        float e1 = SA[1] * ka4[BF][1].CMP;                                   \
        e0 = fmaf(SA[2], ka4[BF][2].CMP, e0);                                \
        e1 = fmaf(SA[3], ka4[BF][3].CMP, e1);                                \
        float p = e0 + e1;                                                   \
        p = allreduce16(p);                                                  \
        float sk0 = rlane(p, 0)  + rlane(p, 16);                             \
        float sk1 = rlane(p, 32) + rlane(p, 48);                             \
        float pown = iA ? sk1 : sk0;                                         \
        float vA   = iA ? vv4[BF][1].CMP : vv4[BF][0].CMP;                   \
        _Pragma("unroll")                                                    \
        for (int u = 0; u < 4; ++u) {                                        \
            float au = aa4[BF][u].CMP;                                       \
            float w = fmaf(-au, pown, vA);                                   \
            SA[u] = fmaf(ma4[BF][u].CMP, w, au * SA[u]);                     \
        }                                                                    \
        float aB0 = aB4[BF][0].CMP, aB1 = aB4[BF][1].CMP;                    \
        float mB0 = mB4[BF][0].CMP, mB1 = mB4[BF][1].CMP;                    \
        float po0 = 0.0f, po1 = 0.0f;                                        \
        _Pragma("unroll")                                                    \
        for (int r = 0; r < 2; ++r) {                                        \
            float skr = r ? sk1 : sk0;                                       \
            float vvr = r ? vv4[BF][1].CMP : vv4[BF][0].CMP;                 \
            float qvr = r ? qv4[BF][1].CMP : qv4[BF][0].CMP;                 \
            float w0 = fmaf(-aB0, skr, vvr);                                 \
            SB[r][0] = fmaf(mB0, w0, aB0 * SB[r][0]);                        \
            po0 = fmaf(qvr, SB[r][0], po0);                                  \
            float w1 = fmaf(-aB1, skr, vvr);                                 \
            SB[r][1] = fmaf(mB1, w1, aB1 * SB[r][1]);                        \
            po1 = fmaf(qvr, SB[r][1], po1);                                  \
        }                                                                    \
        __hip_bfloat162 h2;                                                  \
        h2.x = __float2bfloat16(po0);                                        \
        h2.y = __float2bfloat16(po1);                                        \
        *(__hip_bfloat162*)po = h2;                                          \
        po += DD;                                                            \
    } while (0)

#define STEP4(BF) \
    do { STEPQ(BF, x); STEPQ(BF, y); STEPQ(BF, z); STEPQ(BF, w); } while (0)

    PREB(0);    // block blk0
    PREB(1);    // block blk0+1
    for (int tb = 0; tb < LH / 4; tb += 2) {
        STEP4(0);
        PREB(0);    // blk+2 (final iters overrun into ws: values unused)
        STEP4(1);
        PREB(1);    // blk+3
    }
#undef PREB
#undef STEPQ
#undef STEP4

    {
        float* sp = sout + ((size_t)b * DD + rbase + iA) * DD + colA;
        float4 o4 = {SA[0], SA[1], SA[2], SA[3]};
        *(float4*)sp = o4;
    }
}

// ---------------------------------------------------------------------------
// oc(half) = silu(sum_{g<64} pout[g])  bf16 -> fp32. Writes into the DEAD
// half-band of pack: oc(b,h,tl,d) = ocbase[b*2048*640 + h*1024*640 + tl*128 + d]
// (same byte range as the blocked pack layout's (b, tb<256|>=256) bands).
// ---------------------------------------------------------------------------
__global__ __launch_bounds__(256) void combine_silu_kernel(
    const ushort* __restrict__ pout, float* __restrict__ ocbase, int h)
{
    const size_t NHALF = (size_t)BB * LH * DD;   // elems per slice
    size_t idx = ((size_t)blockIdx.x * 256 + threadIdx.x) * 4;
    float s0 = 0, s1 = 0, s2 = 0, s3 = 0;
#pragma unroll 8
    for (int gi = 0; gi < 64; ++gi) {
        uint2 u = *(const uint2*)(pout + gi * NHALF + idx);
        s0 += __uint_as_float((u.x & 0xffffu) << 16);
        s1 += __uint_as_float(u.x & 0xffff0000u);
        s2 += __uint_as_float((u.y & 0xffffu) << 16);
        s3 += __uint_as_float(u.y & 0xffff0000u);
    }
    float4 r;
    r.x = s0 / (1.0f + __expf(-s0));
    r.y = s1 / (1.0f + __expf(-s1));
    r.z = s2 / (1.0f + __expf(-s2));
    r.w = s3 / (1.0f + __expf(-s3));
    size_t b = idx >> 17;                // / (LH*DD)
    size_t rem = idx & ((size_t)LH * DD - 1);
    float* dst = ocbase + b * (2048ull * 640) + (size_t)h * (1024ull * 640) + rem;
    *(float4*)dst = r;
}

// ---------------------------------------------------------------------------
// d_out = y * rsqrt(mean(y^2)+1e-6) * rms_w + residual. One wave per (b,l).
// ---------------------------------------------------------------------------
__global__ __launch_bounds__(256) void rms_res_kernel(
    const float* __restrict__ y, const float* __restrict__ res,
    const float* __restrict__ rmsw, float* __restrict__ out)
{
    const int tid = threadIdx.x;
    const int lane = tid & 63;
    const int wid = tid >> 6;
    const int m = blockIdx.x * 4 + wid;
    const int d0 = lane * 2;
    size_t o = (size_t)m * DD + d0;
    float2 yv = *(const float2*)(y + o);
    float ss = yv.x * yv.x + yv.y * yv.y;
#pragma unroll
    for (int msk = 1; msk <= 32; msk <<= 1) ss += __shfl_xor(ss, msk);
    float r = rsqrtf(ss * (1.0f / 128.0f) + 1e-6f);
    float2 rv = *(const float2*)(res + o);
    out[o]     = yv.x * r * rmsw[d0]     + rv.x;
    out[o + 1] = yv.y * r * rmsw[d0 + 1] + rv.y;
}

// ---------------------------------------------------------------------------
// Workspace (176,160,768 B total — the R7/R9/R10-proven footprint):
//   [0, 41.9MB)   pack2 blocked [B,512,2560] fp32. After each half's
//                 recurrence that half's band is dead -> combine writes oc.
//   [41.9MB, +134.2MB) poreg:
//      phase 1:  qkv [M,512] + abv [M,256]
//      phase 2:  pout bf16, 64 slices x [B,LH,D]   (reused both halves)
//      phase 3:  res [M,128] + yb [M,128]
// Mid-sequence state lives in sfin (inside d_out): written h0, read h1.
// ---------------------------------------------------------------------------
extern "C" void kernel_launch(void* const* d_in, const int* in_sizes, int n_in,
                              void* d_out, int out_size, void* d_ws, size_t ws_size,
                              hipStream_t stream)
{
    const float* x      = (const float*)d_in[0];
    const float* state  = (const float*)d_in[1];
    const float* W_in   = (const float*)d_in[2];
    const float* W_gate = (const float*)d_in[3];
    const float* W_out  = (const float*)d_in[4];
    const float* W_res  = (const float*)d_in[5];
    const float* qcw    = (const float*)d_in[6];
    const float* qcb    = (const float*)d_in[7];
    const float* kcw    = (const float*)d_in[8];
    const float* kcb    = (const float*)d_in[9];
    const float* rmsw   = (const float*)d_in[10];
    float* out  = (float*)d_out;
    float* sfin = out + (size_t)BB * LL * DD;

    const size_t M = (size_t)BB * LL;            // 16384
    char* base = (char*)d_ws;
    const size_t PACK_BYTES = M * 640 * 4;       // 41.9 MB
    float* pack = (float*)base;
    char*  poreg = base + PACK_BYTES;
    float* qkv = (float*)poreg;                              // phase 1
    float* abv = (float*)(poreg + M * 512 * 4);              // phase 1
    __hip_bfloat16* po = (__hip_bfloat16*)poreg;             // phase 2
    float* res = (float*)poreg;                              // phase 3 (over po)
    float* yb  = (float*)(poreg + M * DD * 4);               // phase 3

    const long ld128 = 128, ld512 = 512;
    dim3 blk(256);
    // qkv = x @ W_in^T  [M,512]
    gemm_kernel<<<dim3(M / 32, 8), blk, 0, stream>>>(
        x, ld128, 2048 * ld128, 1024 * ld128, W_in, qkv, 512, 0);
    // alpha/beta = sigmoid(gate @ W_gate^T) [M,256]
    gemm_kernel<<<dim3(M / 32, 4), blk, 0, stream>>>(
        qkv + 384, ld512, 2048 * ld512, 1024 * ld512, W_gate, abv, 256, 1);
    // conv + sigmoid + l2norm + blocked pack stream [k|m|alpha|q|v] x TB=4
    convnorm_kernel<<<dim3(M / 4), blk, 0, stream>>>(qkv, qcw, qcb, kcw, kcb, abv, pack);
    // recurrence half 0: state -> sfin(mid), partials -> po
    recur2_kernel<<<dim3(BB * 64), dim3(64), 0, stream>>>(pack, state, po, sfin, 0);
    // combine h0 -> oc half 0 (into pack's dead tb<256 bands)
    combine_silu_kernel<<<dim3((BB * LH * DD) / 1024), blk, 0, stream>>>(
        (const ushort*)po, pack, 0);
    // recurrence half 1: sfin(mid) -> sfin(final), partials -> po (reused)
    recur2_kernel<<<dim3(BB * 64), dim3(64), 0, stream>>>(pack, sfin, po, sfin, 256);
    // combine h1 -> oc half 1
    combine_silu_kernel<<<dim3((BB * LH * DD) / 1024), blk, 0, stream>>>(
        (const ushort*)po, pack, 1);
    // residual = x @ W_res^T  (po region dead after combine h1)
    gemm_kernel<<<dim3(M / 32, 2), blk, 0, stream>>>(
        x, ld128, 2048 * ld128, 1024 * ld128, W_res, res, 128, 0);
    // y = oc @ W_out^T   (oc scattered in pack: sB=2048*640, sH=1024*640)
    gemm_kernel<<<dim3(M / 32, 2), blk, 0, stream>>>(
        pack, ld128, 2048 * 640, 1024 * 640, W_out, yb, 128, 0);
    // RMS + residual -> d_out
    rms_res_kernel<<<dim3(M / 4), blk, 0, stream>>>(yb, res, rmsw, out);
}

// Round 12
// 562.652 us; speedup vs baseline: 1.8615x; 1.0922x over previous
//
#include <hip/hip_runtime.h>
#include <hip/hip_bf16.h>
#include <math.h>

#define BB 8
#define LL 2048
#define LQ 512             // quarter sequence (recurrence runs in 4 passes)
#define DD 128

// ---------------------------------------------------------------------------
// DPP helpers: full-rate VALU cross-lane adds (no LDS in the serial chain).
// ---------------------------------------------------------------------------
template <int CTRL>
__device__ __forceinline__ float dpp_add(float x) {
    int xi = __float_as_int(x);
    int yi = __builtin_amdgcn_update_dpp(xi, xi, CTRL, 0xF, 0xF, false);
    return x + __int_as_float(yi);
}
// 16-lane allreduce: ^1, ^2 (quad_perm), ^:8 (half_mirror), ^:16 (mirror)
__device__ __forceinline__ float allreduce16(float p) {
    p = dpp_add<0xB1>(p);
    p = dpp_add<0x4E>(p);
    p = dpp_add<0x141>(p);
    p = dpp_add<0x140>(p);
    return p;
}
__device__ __forceinline__ float rlane(float p, int l) {
    return __int_as_float(__builtin_amdgcn_readlane(__float_as_int(p), l));
}

// ---------------------------------------------------------------------------
// C[M,O] = X @ W[O,128]^T, optional sigmoid. X rows addressed with (batch,
// quarter) strides so the scattered oc layout works: row m -> b=m>>11,
// t=m&2047, q=t>>9, tl=t&511; addr = X + b*sB + q*sQ + tl*ldx.
// ---------------------------------------------------------------------------
__global__ __launch_bounds__(256) void gemm_kernel(
    const float* __restrict__ X, long ldx, long sB, long sQ,
    const float* __restrict__ W,
    float* __restrict__ C, int ldc,
    int applySig)
{
    __shared__ float Xs[32 * 132];
    __shared__ float Ws[64 * 132];
    const int tid = threadIdx.x;
    const int m0 = blockIdx.x * 32;
    const int o0 = blockIdx.y * 64;
    {
        int row = tid >> 3, cg = tid & 7;
        int m = m0 + row;
        int b = m >> 11, t = m & 2047, qq = t >> 9, tl = t & 511;
        const float* src = X + (size_t)b * sB + (size_t)qq * sQ
                             + (size_t)tl * ldx + cg * 16;
        float* dst = Xs + row * 132 + cg * 16;
#pragma unroll
        for (int u = 0; u < 4; ++u)
            *(float4*)(dst + 4 * u) = *(const float4*)(src + 4 * u);
    }
    {
        int o = tid >> 2, cg = tid & 3;
        const float* src = W + (size_t)(o0 + o) * 128 + cg * 32;
        float* dst = Ws + o * 132 + cg * 32;
#pragma unroll
        for (int u = 0; u < 8; ++u)
            *(float4*)(dst + 4 * u) = *(const float4*)(src + 4 * u);
    }
    __syncthreads();
    const int tx = tid & 31, ty = tid >> 5;
    float acc[4][2] = {};
    const float* xb = Xs + (ty * 4) * 132;
    const float* wb = Ws + (tx * 2) * 132;
    for (int k0 = 0; k0 < 128; k0 += 4) {
        float4 xr[4], wr[2];
#pragma unroll
        for (int r = 0; r < 4; ++r) xr[r] = *(const float4*)(xb + r * 132 + k0);
#pragma unroll
        for (int cc = 0; cc < 2; ++cc) wr[cc] = *(const float4*)(wb + cc * 132 + k0);
#pragma unroll
        for (int r = 0; r < 4; ++r)
#pragma unroll
            for (int cc = 0; cc < 2; ++cc) {
                acc[r][cc] += xr[r].x * wr[cc].x + xr[r].y * wr[cc].y
                            + xr[r].z * wr[cc].z + xr[r].w * wr[cc].w;
            }
    }
#pragma unroll
    for (int r = 0; r < 4; ++r)
#pragma unroll
        for (int cc = 0; cc < 2; ++cc) {
            float v = acc[r][cc];
            if (applySig) v = 1.0f / (1.0f + __expf(-v));
            C[(size_t)(m0 + ty * 4 + r) * ldc + o0 + tx * 2 + cc] = v;
        }
}

// ---------------------------------------------------------------------------
// Depthwise conv(K=3) + sigmoid + L2-norm for q,k; packs the recurrence
// stream TIME-BLOCKED (TB=4): for batch b, block tb=t>>2, ti=t&3:
//   pack2[(b*512 + tb)*2560 + (o*128 + d)*4 + ti],  o in {k,m,a,q,v}
// so one float4 load in the recurrence yields 4 timesteps of one scalar.
// ---------------------------------------------------------------------------
__global__ __launch_bounds__(256) void convnorm_kernel(
    const float* __restrict__ qkv,
    const float* __restrict__ qw, const float* __restrict__ qb,
    const float* __restrict__ kw, const float* __restrict__ kb,
    const float* __restrict__ ab,
    float* __restrict__ pack)
{
    const int tid = threadIdx.x;
    const int lane = tid & 63;
    const int wid = tid >> 6;
    const int m = blockIdx.x * 4 + wid;     // b*L + l
    const int l = m & (LL - 1);
    const int b = m >> 11;
    const int d0 = lane * 2;
    float yq0 = qb[d0], yq1 = qb[d0 + 1];
    float yk0 = kb[d0], yk1 = kb[d0 + 1];
#pragma unroll
    for (int tau = 0; tau < 3; ++tau) {
        int lp = l + tau - 1;
        if (lp >= 0 && lp < LL) {
            const float* base = qkv + (size_t)(m + tau - 1) * 512;
            yq0 += base[d0]       * qw[d0 * 3 + tau];
            yq1 += base[d0 + 1]   * qw[(d0 + 1) * 3 + tau];
            yk0 += base[128 + d0]     * kw[d0 * 3 + tau];
            yk1 += base[128 + d0 + 1] * kw[(d0 + 1) * 3 + tau];
        }
    }
    yq0 = 1.0f / (1.0f + __expf(-yq0));
    yq1 = 1.0f / (1.0f + __expf(-yq1));
    yk0 = 1.0f / (1.0f + __expf(-yk0));
    yk1 = 1.0f / (1.0f + __expf(-yk1));
    float sq = yq0 * yq0 + yq1 * yq1;
    float sk = yk0 * yk0 + yk1 * yk1;
#pragma unroll
    for (int msk = 1; msk <= 32; msk <<= 1) {
        sq += __shfl_xor(sq, msk);
        sk += __shfl_xor(sk, msk);
    }
    float rq = 1.0f / fmaxf(sqrtf(sq), 1e-12f);
    float rk = 1.0f / fmaxf(sqrtf(sk), 1e-12f);
    float k0n = yk0 * rk, k1n = yk1 * rk;
    float a0 = ab[(size_t)m * 256 + d0];
    float a1 = ab[(size_t)m * 256 + d0 + 1];
    float b0 = ab[(size_t)m * 256 + 128 + d0];
    float b1 = ab[(size_t)m * 256 + 128 + d0 + 1];
    float v0 = qkv[(size_t)m * 512 + 256 + d0];
    float v1 = qkv[(size_t)m * 512 + 256 + d0 + 1];
    float* P = pack + ((size_t)b * 512 + (l >> 2)) * 2560 + (l & 3);
    P[d0 * 4]              = k0n;      P[(d0 + 1) * 4]        = k1n;
    P[512 + d0 * 4]        = b0 * k0n; P[512 + (d0 + 1) * 4]  = b1 * k1n;
    P[1024 + d0 * 4]       = a0;       P[1024 + (d0 + 1) * 4] = a1;
    P[1536 + d0 * 4]       = yq0 * rq; P[1536 + (d0 + 1) * 4] = yq1 * rq;
    P[2048 + d0 * 4]       = v0;       P[2048 + (d0 + 1) * 4] = v1;
}

// ---------------------------------------------------------------------------
// Barrier-free delta-rule recurrence, R=1 row/wave, QUARTER sequence/call.
// Grid 1024 = BB*128 one-wave WGs -> 1 wave per SIMD chip-wide.
// With one row the A and B layouts COINCIDE: lane holds S[g][2l..2l+2) in
// SA[2]; no dual state, no iA/pown selects. Per step:
//   dot(2) -> allreduce16 -> 4 readlane + 3 add (full row-dot, uniform)
//   -> 2x(3-op col update) -> 2 muls -> packed bf16 store     (~26 VALU)
// TB=4 blocked operands, depth-2 block pipeline, sched_barrier(0) after
// each PREB (R11: pins load-issue, keeps both buffers live).
// Partials: bf16, pout[g][b][tl][d], g in [0,128), tl in [0,LQ).
// ---------------------------------------------------------------------------
__global__ __launch_bounds__(64, 1) void recur1_kernel(
    const float* __restrict__ pack, const float* __restrict__ sin,
    __hip_bfloat16* __restrict__ pout, float* __restrict__ sout, int blk0)
{
    const int lane = threadIdx.x;
    const int b = blockIdx.x >> 7;
    const int g = blockIdx.x & 127;
    const int j0 = lane * 2;

    float SA[2];
    {
        const float* sp = sin + ((size_t)b * DD + g) * DD + j0;
        float2 t2 = *(const float2*)sp;
        SA[0] = t2.x; SA[1] = t2.y;
    }

    const float* P = pack + ((size_t)b * 512 + blk0) * 2560;
    __hip_bfloat16* po = pout + ((size_t)g * (BB * LQ) + (size_t)b * LQ) * DD + j0;

    // block-level double buffers (statically indexed)
    float4 ka4[2][2], ma4[2][2], aa4[2][2];
    float4 qv4[2], vv4[2];

#define PREB(BF)                                                             \
    do {                                                                     \
        ka4[BF][0] = *(const float4*)(P + j0 * 4);                           \
        ka4[BF][1] = *(const float4*)(P + j0 * 4 + 4);                       \
        ma4[BF][0] = *(const float4*)(P + 512 + j0 * 4);                     \
        ma4[BF][1] = *(const float4*)(P + 512 + j0 * 4 + 4);                 \
        aa4[BF][0] = *(const float4*)(P + 1024 + j0 * 4);                    \
        aa4[BF][1] = *(const float4*)(P + 1024 + j0 * 4 + 4);                \
        qv4[BF]    = *(const float4*)(P + 1536 + g * 4);                     \
        vv4[BF]    = *(const float4*)(P + 2048 + g * 4);                     \
        P += 2560;                                                           \
        __builtin_amdgcn_sched_barrier(0);  /* pin load-issue point */       \
    } while (0)

#define STEPQ(BF, CMP)                                                       \
    do {                                                                     \
        float e = SA[0] * ka4[BF][0].CMP;                                    \
        e = fmaf(SA[1], ka4[BF][1].CMP, e);                                  \
        float p = allreduce16(e);                                            \
        float sk = (rlane(p, 0) + rlane(p, 16))                              \
                 + (rlane(p, 32) + rlane(p, 48));                            \
        float vg = vv4[BF].CMP, qg = qv4[BF].CMP;                            \
        float a0 = aa4[BF][0].CMP, a1 = aa4[BF][1].CMP;                      \
        float w0 = fmaf(-a0, sk, vg);                                        \
        SA[0] = fmaf(ma4[BF][0].CMP, w0, a0 * SA[0]);                        \
        float w1 = fmaf(-a1, sk, vg);                                        \
        SA[1] = fmaf(ma4[BF][1].CMP, w1, a1 * SA[1]);                        \
        __hip_bfloat162 h2;                                                  \
        h2.x = __float2bfloat16(qg * SA[0]);                                 \
        h2.y = __float2bfloat16(qg * SA[1]);                                 \
        *(__hip_bfloat162*)po = h2;                                          \
        po += DD;                                                            \
    } while (0)

#define STEP4(BF) \
    do { STEPQ(BF, x); STEPQ(BF, y); STEPQ(BF, z); STEPQ(BF, w); } while (0)

    PREB(0);    // block blk0
    PREB(1);    // block blk0+1
    for (int tb = 0; tb < LQ / 4; tb += 2) {
        STEP4(0);
        PREB(0);    // blk+2 (final iters overrun into ws: values unused)
        STEP4(1);
        PREB(1);    // blk+3
    }
#undef PREB
#undef STEPQ
#undef STEP4

    {
        float* sp = sout + ((size_t)b * DD + g) * DD + j0;
        float2 o2 = {SA[0], SA[1]};
        *(float2*)sp = o2;
    }
}

// ---------------------------------------------------------------------------
// oc(quarter) = silu(sum_{g<128} pout[g])  bf16 -> fp32. Writes into the
// DEAD quarter-band of pack:
//   oc(b,q,tl,d) = ocbase[b*512*2560 + q*128*2560 + tl*128 + d]
// (tl*128+d < 65536 < 327680 = quarter band size: fits.)
// ---------------------------------------------------------------------------
__global__ __launch_bounds__(256) void combine_silu_kernel(
    const ushort* __restrict__ pout, float* __restrict__ ocbase, int q)
{
    const size_t NQ = (size_t)BB * LQ * DD;   // 524288 elems per slice
    size_t idx = ((size_t)blockIdx.x * 256 + threadIdx.x) * 4;
    float s0 = 0, s1 = 0, s2 = 0, s3 = 0;
#pragma unroll 8
    for (int gi = 0; gi < 128; ++gi) {
        uint2 u = *(const uint2*)(pout + gi * NQ + idx);
        s0 += __uint_as_float((u.x & 0xffffu) << 16);
        s1 += __uint_as_float(u.x & 0xffff0000u);
        s2 += __uint_as_float((u.y & 0xffffu) << 16);
        s3 += __uint_as_float(u.y & 0xffff0000u);
    }
    float4 r;
    r.x = s0 / (1.0f + __expf(-s0));
    r.y = s1 / (1.0f + __expf(-s1));
    r.z = s2 / (1.0f + __expf(-s2));
    r.w = s3 / (1.0f + __expf(-s3));
    size_t b = idx >> 16;                 // / (LQ*DD)
    size_t rem = idx & ((size_t)LQ * DD - 1);
    float* dst = ocbase + b * (512ull * 2560) + (size_t)q * (128ull * 2560) + rem;
    *(float4*)dst = r;
}

// ---------------------------------------------------------------------------
// d_out = y * rsqrt(mean(y^2)+1e-6) * rms_w + residual. One wave per (b,l).
// ---------------------------------------------------------------------------
__global__ __launch_bounds__(256) void rms_res_kernel(
    const float* __restrict__ y, const float* __restrict__ res,
    const float* __restrict__ rmsw, float* __restrict__ out)
{
    const int tid = threadIdx.x;
    const int lane = tid & 63;
    const int wid = tid >> 6;
    const int m = blockIdx.x * 4 + wid;
    const int d0 = lane * 2;
    size_t o = (size_t)m * DD + d0;
    float2 yv = *(const float2*)(y + o);
    float ss = yv.x * yv.x + yv.y * yv.y;
#pragma unroll
    for (int msk = 1; msk <= 32; msk <<= 1) ss += __shfl_xor(ss, msk);
    float r = rsqrtf(ss * (1.0f / 128.0f) + 1e-6f);
    float2 rv = *(const float2*)(res + o);
    out[o]     = yv.x * r * rmsw[d0]     + rv.x;
    out[o + 1] = yv.y * r * rmsw[d0 + 1] + rv.y;
}

// ---------------------------------------------------------------------------
// Workspace (176,160,768 B total — the R7..R11-proven footprint):
//   [0, 41.9MB)   pack2 blocked [B,512,2560] fp32. After each quarter's
//                 recurrence that quarter's band is dead -> combine -> oc.
//   [41.9MB, +134.2MB) poreg:
//      phase 1:  qkv [M,512] + abv [M,256]
//      phase 2:  pout bf16, 128 slices x [B,LQ,D]  (reused for 4 quarters)
//      phase 3:  res [M,128] + yb [M,128]
// Inter-pass state lives in sfin (inside d_out): written pass q, read q+1.
// ---------------------------------------------------------------------------
extern "C" void kernel_launch(void* const* d_in, const int* in_sizes, int n_in,
                              void* d_out, int out_size, void* d_ws, size_t ws_size,
                              hipStream_t stream)
{
    const float* x      = (const float*)d_in[0];
    const float* state  = (const float*)d_in[1];
    const float* W_in   = (const float*)d_in[2];
    const float* W_gate = (const float*)d_in[3];
    const float* W_out  = (const float*)d_in[4];
    const float* W_res  = (const float*)d_in[5];
    const float* qcw    = (const float*)d_in[6];
    const float* qcb    = (const float*)d_in[7];
    const float* kcw    = (const float*)d_in[8];
    const float* kcb    = (const float*)d_in[9];
    const float* rmsw   = (const float*)d_in[10];
    float* out  = (float*)d_out;
    float* sfin = out + (size_t)BB * LL * DD;

    const size_t M = (size_t)BB * LL;            // 16384
    char* base = (char*)d_ws;
    const size_t PACK_BYTES = M * 640 * 4;       // 41.9 MB
    float* pack = (float*)base;
    char*  poreg = base + PACK_BYTES;
    float* qkv = (float*)poreg;                              // phase 1
    float* abv = (float*)(poreg + M * 512 * 4);              // phase 1
    __hip_bfloat16* po = (__hip_bfloat16*)poreg;             // phase 2
    float* res = (float*)poreg;                              // phase 3 (over po)
    float* yb  = (float*)(poreg + M * DD * 4);               // phase 3

    dim3 blk(256);
    // qkv = x @ W_in^T  [M,512]
    gemm_kernel<<<dim3(M / 32, 8), blk, 0, stream>>>(
        x, 128, 2048L * 128, 512L * 128, W_in, qkv, 512, 0);
    // alpha/beta = sigmoid(gate @ W_gate^T) [M,256]
    gemm_kernel<<<dim3(M / 32, 4), blk, 0, stream>>>(
        qkv + 384, 512, 2048L * 512, 512L * 512, W_gate, abv, 256, 1);
    // conv + sigmoid + l2norm + blocked pack stream [k|m|alpha|q|v] x TB=4
    convnorm_kernel<<<dim3(M / 4), blk, 0, stream>>>(qkv, qcw, qcb, kcw, kcb, abv, pack);
    // recurrence in 4 quarter passes; state relayed through sfin
    for (int q = 0; q < 4; ++q) {
        const float* sin = (q == 0) ? state : sfin;
        recur1_kernel<<<dim3(BB * 128), dim3(64), 0, stream>>>(
            pack, sin, po, sfin, q * 128);
        combine_silu_kernel<<<dim3(512), blk, 0, stream>>>(
            (const ushort*)po, pack, q);
    }
    // residual = x @ W_res^T  (po region dead after last combine)
    gemm_kernel<<<dim3(M / 32, 2), blk, 0, stream>>>(
        x, 128, 2048L * 128, 512L * 128, W_res, res, 128, 0);
    // y = oc @ W_out^T   (oc scattered in pack: sB=512*2560, sQ=128*2560)
    gemm_kernel<<<dim3(M / 32, 2), blk, 0, stream>>>(
        pack, 128, 512L * 2560, 128L * 2560, W_out, yb, 128, 0);
    // RMS + residual -> d_out
    rms_res_kernel<<<dim3(M / 4), blk, 0, stream>>>(yb, res, rmsw, out);
}